// Round 1
// baseline (8035.999 us; speedup 1.0000x reference)
//
#include <hip/hip_runtime.h>
#include <hip/hip_bf16.h>

#define IMG    56
#define CH     128
#define QKVC   384
#define S2     49
#define HD     32
#define NHEADS 4
#define DSP    3

// One block per (batch, window). 384 threads = 6 waves.
// LDS: ldsA   = xw [49][128] f32 (later reused for attn [49][128] f32)  25088 B
//      ldsQKV = qkv [49][384] bf16                                      37632 B
//      ldsPE  = pos_embedding 13x13 f32                                   676 B
// total 63396 B < 64 KiB -> 2 blocks/CU possible (160 KiB LDS/CU).
__global__ __launch_bounds__(384, 3)
void swin_fused(const float* __restrict__ x,
                const float* __restrict__ w_qkv,
                const float* __restrict__ pe,
                const float* __restrict__ w_out,
                const float* __restrict__ b_out,
                float* __restrict__ out)
{
    __shared__ float          ldsA[S2 * CH];
    __shared__ __hip_bfloat16 ldsQKV[S2 * QKVC];
    __shared__ float          ldsPE[169];

    const int tid = (int)threadIdx.x;
    const int b   = (int)blockIdx.y;
    const int wh  = (int)blockIdx.x >> 3;   // window row 0..7
    const int ww  = (int)blockIdx.x & 7;    // window col 0..7

    // ---- phase 0: load pos table + rolled x-window into LDS ----
    if (tid < 169) ldsPE[tid] = pe[tid];

    for (int idx = tid; idx < S2 * 32; idx += 384) {
        const int s  = idx >> 5;            // token 0..48
        const int c4 = (idx & 31) << 2;     // channel (float4 granularity)
        const int iy = s / 7, ix = s - iy * 7;
        int gy = wh * 7 + iy + DSP; if (gy >= IMG) gy -= IMG;   // roll(-3): read x[(r+3)%56]
        int gx = ww * 7 + ix + DSP; if (gx >= IMG) gx -= IMG;
        const float4 v = *(const float4*)(x + (size_t)((b * IMG + gy) * IMG + gx) * CH + c4);
        *(float4*)(ldsA + s * CH + c4) = v;
    }
    __syncthreads();

    // ---- phase 1: qkv = xw @ w_qkv^T ; thread t owns output column t (0..383) ----
    {
        const float* wrow = w_qkv + tid * CH;
        float acc[S2];
        #pragma unroll
        for (int i = 0; i < S2; ++i) acc[i] = 0.f;
        #pragma unroll 2
        for (int k = 0; k < CH; k += 4) {
            const float4 wv = *(const float4*)(wrow + k);
            #pragma unroll
            for (int i = 0; i < S2; ++i) {
                const float4 xv = *(const float4*)(ldsA + i * CH + k);  // wave-broadcast
                acc[i] += xv.x * wv.x;
                acc[i] += xv.y * wv.y;
                acc[i] += xv.z * wv.z;
                acc[i] += xv.w * wv.w;
            }
        }
        #pragma unroll
        for (int i = 0; i < S2; ++i)
            ldsQKV[i * QKVC + tid] = __float2bfloat16(acc[i]);
    }
    __syncthreads();

    // ---- phases 2+3: attention. wave = head, lane = query row ----
    const int wave = tid >> 6;
    const int lane = tid & 63;
    if (wave < NHEADS && lane < S2) {
        const int h = wave, r = lane;
        const int iy = r / 7, ix = r - iy * 7;
        const int ibase = 84 - (iy * 13 + ix);       // bias idx = jy*13+jx + ibase
        const bool my = (wh == 7), mx = (ww == 7);
        const bool riy = (iy >= 4), rix = (ix >= 4);

        // q row -> 32 fp32 regs
        float q[HD];
        {
            const uint4* qp = (const uint4*)(ldsQKV + r * QKVC + h * HD);
            #pragma unroll
            for (int t = 0; t < 4; ++t) {
                const uint4 u = qp[t];
                q[t*8+0] = __uint_as_float(u.x << 16);
                q[t*8+1] = __uint_as_float(u.x & 0xffff0000u);
                q[t*8+2] = __uint_as_float(u.y << 16);
                q[t*8+3] = __uint_as_float(u.y & 0xffff0000u);
                q[t*8+4] = __uint_as_float(u.z << 16);
                q[t*8+5] = __uint_as_float(u.z & 0xffff0000u);
                q[t*8+6] = __uint_as_float(u.w << 16);
                q[t*8+7] = __uint_as_float(u.w & 0xffff0000u);
            }
        }

        float sc[S2];
        #pragma unroll
        for (int j = 0; j < S2; ++j) {
            const int jy = j / 7, jx = j - jy * 7;
            const uint4* kp = (const uint4*)(ldsQKV + j * QKVC + CH + h * HD); // k row, wave-broadcast
            float a0 = 0.f, a1 = 0.f, a2 = 0.f, a3 = 0.f;
            #pragma unroll
            for (int t = 0; t < 4; ++t) {
                const uint4 u = kp[t];
                a0 += q[t*8+0] * __uint_as_float(u.x << 16);
                a1 += q[t*8+1] * __uint_as_float(u.x & 0xffff0000u);
                a2 += q[t*8+2] * __uint_as_float(u.y << 16);
                a3 += q[t*8+3] * __uint_as_float(u.y & 0xffff0000u);
                a0 += q[t*8+4] * __uint_as_float(u.z << 16);
                a1 += q[t*8+5] * __uint_as_float(u.z & 0xffff0000u);
                a2 += q[t*8+6] * __uint_as_float(u.w << 16);
                a3 += q[t*8+7] * __uint_as_float(u.w & 0xffff0000u);
            }
            float s = ((a0 + a1) + (a2 + a3)) * 0.5f;           // SCALE = HEADS^-0.5 = 0.5
            s += ldsPE[jy * 13 + jx + ibase];                   // relative-position bias
            if (my && (riy != (jy >= 4))) s = -1e30f;           // shifted-window masks
            if (mx && (rix != (jx >= 4))) s = -1e30f;
            sc[j] = s;
        }

        // softmax (fully in-lane)
        float mval = sc[0];
        #pragma unroll
        for (int j = 1; j < S2; ++j) mval = fmaxf(mval, sc[j]);
        float sum = 0.f;
        #pragma unroll
        for (int j = 0; j < S2; ++j) { const float e = __expf(sc[j] - mval); sc[j] = e; sum += e; }
        const float inv = 1.0f / sum;

        // P @ V
        float o[HD];
        #pragma unroll
        for (int d = 0; d < HD; ++d) o[d] = 0.f;
        #pragma unroll
        for (int j = 0; j < S2; ++j) {
            const float p = sc[j];
            const uint4* vp = (const uint4*)(ldsQKV + j * QKVC + 2 * CH + h * HD); // wave-broadcast
            #pragma unroll
            for (int t = 0; t < 4; ++t) {
                const uint4 u = vp[t];
                o[t*8+0] += p * __uint_as_float(u.x << 16);
                o[t*8+1] += p * __uint_as_float(u.x & 0xffff0000u);
                o[t*8+2] += p * __uint_as_float(u.y << 16);
                o[t*8+3] += p * __uint_as_float(u.y & 0xffff0000u);
                o[t*8+4] += p * __uint_as_float(u.z << 16);
                o[t*8+5] += p * __uint_as_float(u.z & 0xffff0000u);
                o[t*8+6] += p * __uint_as_float(u.w << 16);
                o[t*8+7] += p * __uint_as_float(u.w & 0xffff0000u);
            }
        }
        #pragma unroll
        for (int d = 0; d < HD; d += 4) {
            float4 v;
            v.x = o[d+0] * inv; v.y = o[d+1] * inv;
            v.z = o[d+2] * inv; v.w = o[d+3] * inv;
            *(float4*)(ldsA + r * CH + h * HD + d) = v;   // attn overwrites xw region
        }
    }
    __syncthreads();

    // ---- phase 4: out = attn @ w_out^T + b_out, scattered to roll(+3) position ----
    {
        const int o  = tid & 127;     // output channel
        const int sg = tid >> 7;      // row group 0..2
        const float bo = b_out[o];
        const float* wrow = w_out + o * CH;
        for (int s = sg; s < S2; s += 3) {
            float a0 = 0.f, a1 = 0.f, a2 = 0.f, a3 = 0.f;
            #pragma unroll
            for (int k = 0; k < CH; k += 4) {
                const float4 av = *(const float4*)(ldsA + s * CH + k);  // wave-broadcast
                const float4 wv = *(const float4*)(wrow + k);
                a0 += av.x * wv.x; a1 += av.y * wv.y;
                a2 += av.z * wv.z; a3 += av.w * wv.w;
            }
            const int sy = s / 7, sx = s - sy * 7;
            int gy = wh * 7 + sy + DSP; if (gy >= IMG) gy -= IMG;   // roll(+3) == same coord as gather
            int gx = ww * 7 + sx + DSP; if (gx >= IMG) gx -= IMG;
            out[(size_t)((b * IMG + gy) * IMG + gx) * CH + o] = (a0 + a1) + (a2 + a3) + bo;
        }
    }
}

extern "C" void kernel_launch(void* const* d_in, const int* in_sizes, int n_in,
                              void* d_out, int out_size, void* d_ws, size_t ws_size,
                              hipStream_t stream) {
    const float* x      = (const float*)d_in[0];
    const float* w_qkv  = (const float*)d_in[1];
    const float* pe     = (const float*)d_in[2];
    const float* w_out  = (const float*)d_in[3];
    const float* b_out  = (const float*)d_in[4];
    float* out = (float*)d_out;

    dim3 grid(64, 64);   // (windows, batch)
    swin_fused<<<grid, 384, 0, stream>>>(x, w_qkv, pe, w_out, b_out, out);
}

// Round 2
// 622.486 us; speedup vs baseline: 12.9095x; 12.9095x over previous
//
#include <hip/hip_runtime.h>
#include <hip/hip_bf16.h>

#define IMG    56
#define CH     128
#define QKVC   384
#define S2     49
#define HD     32
#define DSP    3
#define LDA    136   // ldsA row stride (bf16 elems): 272 B -> bank rotation 4/row
#define LDQ    392   // ldsQKV row stride (bf16 elems): 784 B -> bank rotation 4/row

typedef __attribute__((ext_vector_type(8))) short bf16x8;
typedef __attribute__((ext_vector_type(4))) float f32x4;

// float -> bf16 bits, round-to-nearest-even (inputs are finite; no NaN path needed)
__device__ __forceinline__ unsigned short f2bs(float f) {
    unsigned u = __float_as_uint(f);
    return (unsigned short)((u + 0x7fffu + ((u >> 16) & 1u)) >> 16);
}
__device__ __forceinline__ float bs2f(unsigned u) {        // low 16 bits -> float
    return __uint_as_float(u << 16);
}
__device__ __forceinline__ float bs2f_hi(unsigned u) {     // high 16 bits -> float
    return __uint_as_float(u & 0xffff0000u);
}

// One block per (batch, window). 256 threads = 4 waves.
// Phase 1 & 4: bf16 MFMA 16x16x32. Phase 2/3 (attention): VALU, wave=head, lane=row.
__global__ __launch_bounds__(256, 2)
void swin_fused(const float* __restrict__ x,
                const float* __restrict__ w_qkv,
                const float* __restrict__ pe,
                const float* __restrict__ w_out,
                const float* __restrict__ b_out,
                float* __restrict__ out)
{
    __shared__ unsigned short ldsA[64 * LDA];   // bf16 A: x-window (phase1), attn (phase4)
    __shared__ unsigned short ldsQKV[S2 * LDQ]; // bf16 qkv[49][384]
    __shared__ float          ldsPE[169];

    const int tid  = (int)threadIdx.x;
    const int wave = tid >> 6;
    const int lane = tid & 63;
    const int b    = (int)blockIdx.y;
    const int wh   = (int)blockIdx.x >> 3;
    const int ww   = (int)blockIdx.x & 7;

    if (tid < 169) ldsPE[tid] = pe[tid];

    // ---- phase 0: rolled x-window -> bf16 LDS ----
    for (int idx = tid; idx < S2 * 32; idx += 256) {
        const int s  = idx >> 5;
        const int c4 = (idx & 31) << 2;
        const int iy = s / 7, ix = s - iy * 7;
        int gy = wh * 7 + iy + DSP; if (gy >= IMG) gy -= IMG;
        int gx = ww * 7 + ix + DSP; if (gx >= IMG) gx -= IMG;
        const float4 v = *(const float4*)(x + (size_t)((b * IMG + gy) * IMG + gx) * CH + c4);
        uint2 p;
        p.x = (unsigned)f2bs(v.x) | ((unsigned)f2bs(v.y) << 16);
        p.y = (unsigned)f2bs(v.z) | ((unsigned)f2bs(v.w) << 16);
        *(uint2*)(ldsA + s * LDA + c4) = p;
    }
    __syncthreads();

    // ---- phase 1: qkv[49][384] = A[49][128] @ w_qkv^T  (MFMA, wave owns 6 n-tiles) ----
    {
        const int lm = lane & 15, lq = lane >> 4;
        bf16x8 af[4][4];
        #pragma unroll
        for (int mt = 0; mt < 4; ++mt)
            #pragma unroll
            for (int kt = 0; kt < 4; ++kt)
                af[mt][kt] = *(const bf16x8*)(ldsA + (mt * 16 + lm) * LDA + kt * 32 + lq * 8);

        #pragma unroll
        for (int nt = 0; nt < 6; ++nt) {
            const int n0 = (wave * 6 + nt) * 16;
            const float* wb = w_qkv + (size_t)(n0 + lm) * CH + lq * 8;
            bf16x8 bf[4];
            #pragma unroll
            for (int kt = 0; kt < 4; ++kt) {
                const float4 u0 = *(const float4*)(wb + kt * 32);
                const float4 u1 = *(const float4*)(wb + kt * 32 + 4);
                bf16x8 t;
                t[0] = (short)f2bs(u0.x); t[1] = (short)f2bs(u0.y);
                t[2] = (short)f2bs(u0.z); t[3] = (short)f2bs(u0.w);
                t[4] = (short)f2bs(u1.x); t[5] = (short)f2bs(u1.y);
                t[6] = (short)f2bs(u1.z); t[7] = (short)f2bs(u1.w);
                bf[kt] = t;
            }
            f32x4 c0 = {0.f,0.f,0.f,0.f}, c1 = {0.f,0.f,0.f,0.f};
            f32x4 c2 = {0.f,0.f,0.f,0.f}, c3 = {0.f,0.f,0.f,0.f};
            #pragma unroll
            for (int kt = 0; kt < 4; ++kt) {
                c0 = __builtin_amdgcn_mfma_f32_16x16x32_bf16(af[0][kt], bf[kt], c0, 0, 0, 0);
                c1 = __builtin_amdgcn_mfma_f32_16x16x32_bf16(af[1][kt], bf[kt], c1, 0, 0, 0);
                c2 = __builtin_amdgcn_mfma_f32_16x16x32_bf16(af[2][kt], bf[kt], c2, 0, 0, 0);
                c3 = __builtin_amdgcn_mfma_f32_16x16x32_bf16(af[3][kt], bf[kt], c3, 0, 0, 0);
            }
            const int col = n0 + lm;
            #pragma unroll
            for (int mt = 0; mt < 4; ++mt) {
                const f32x4 c = (mt == 0) ? c0 : (mt == 1) ? c1 : (mt == 2) ? c2 : c3;
                const int rb = mt * 16 + lq * 4;
                #pragma unroll
                for (int r = 0; r < 4; ++r)
                    if (rb + r < S2)
                        ldsQKV[(rb + r) * LDQ + col] = f2bs(c[r]);
            }
        }
    }
    __syncthreads();

    // ---- phases 2+3: attention. wave = head, lane = query row ----
    if (lane < S2) {
        const int h = wave, r = lane;
        const int iy = r / 7, ix = r - iy * 7;
        const int ibase = 84 - (iy * 13 + ix);
        const bool my = (wh == 7), mx = (ww == 7);
        const bool riy = (iy >= 4), rix = (ix >= 4);

        float q[HD];
        {
            const uint4* qp = (const uint4*)(ldsQKV + r * LDQ + h * HD);
            #pragma unroll
            for (int t = 0; t < 4; ++t) {
                const uint4 u = qp[t];
                q[t*8+0] = bs2f(u.x);    q[t*8+1] = bs2f_hi(u.x);
                q[t*8+2] = bs2f(u.y);    q[t*8+3] = bs2f_hi(u.y);
                q[t*8+4] = bs2f(u.z);    q[t*8+5] = bs2f_hi(u.z);
                q[t*8+6] = bs2f(u.w);    q[t*8+7] = bs2f_hi(u.w);
            }
        }

        float sc[S2];
        #pragma unroll
        for (int j = 0; j < S2; ++j) {
            const int jy = j / 7, jx = j - jy * 7;
            const uint4* kp = (const uint4*)(ldsQKV + j * LDQ + CH + h * HD);
            float a0 = 0.f, a1 = 0.f, a2 = 0.f, a3 = 0.f;
            #pragma unroll
            for (int t = 0; t < 4; ++t) {
                const uint4 u = kp[t];
                a0 += q[t*8+0] * bs2f(u.x);    a1 += q[t*8+1] * bs2f_hi(u.x);
                a2 += q[t*8+2] * bs2f(u.y);    a3 += q[t*8+3] * bs2f_hi(u.y);
                a0 += q[t*8+4] * bs2f(u.z);    a1 += q[t*8+5] * bs2f_hi(u.z);
                a2 += q[t*8+6] * bs2f(u.w);    a3 += q[t*8+7] * bs2f_hi(u.w);
            }
            float s = ((a0 + a1) + (a2 + a3)) * 0.5f;
            s += ldsPE[jy * 13 + jx + ibase];
            if (my && (riy != (jy >= 4))) s = -1e30f;
            if (mx && (rix != (jx >= 4))) s = -1e30f;
            sc[j] = s;
        }

        float mval = sc[0];
        #pragma unroll
        for (int j = 1; j < S2; ++j) mval = fmaxf(mval, sc[j]);
        float sum = 0.f;
        #pragma unroll
        for (int j = 0; j < S2; ++j) { const float e = __expf(sc[j] - mval); sc[j] = e; sum += e; }
        const float inv = 1.0f / sum;

        float o[HD];
        #pragma unroll
        for (int d = 0; d < HD; ++d) o[d] = 0.f;
        #pragma unroll
        for (int j = 0; j < S2; ++j) {
            const float p = sc[j];
            const uint4* vp = (const uint4*)(ldsQKV + j * LDQ + 2 * CH + h * HD);
            #pragma unroll
            for (int t = 0; t < 4; ++t) {
                const uint4 u = vp[t];
                o[t*8+0] += p * bs2f(u.x);    o[t*8+1] += p * bs2f_hi(u.x);
                o[t*8+2] += p * bs2f(u.y);    o[t*8+3] += p * bs2f_hi(u.y);
                o[t*8+4] += p * bs2f(u.z);    o[t*8+5] += p * bs2f_hi(u.z);
                o[t*8+6] += p * bs2f(u.w);    o[t*8+7] += p * bs2f_hi(u.w);
            }
        }
        #pragma unroll
        for (int d = 0; d < HD; d += 2) {
            const unsigned p = (unsigned)f2bs(o[d] * inv) | ((unsigned)f2bs(o[d+1] * inv) << 16);
            *(unsigned*)(ldsA + r * LDA + h * HD + d) = p;
        }
    }
    __syncthreads();

    // ---- phase 4: out[49][128] = attn @ w_out^T + b_out (MFMA, wave owns 2 n-tiles) ----
    {
        const int lm = lane & 15, lq = lane >> 4;
        bf16x8 af[4][4];
        #pragma unroll
        for (int mt = 0; mt < 4; ++mt)
            #pragma unroll
            for (int kt = 0; kt < 4; ++kt)
                af[mt][kt] = *(const bf16x8*)(ldsA + (mt * 16 + lm) * LDA + kt * 32 + lq * 8);

        #pragma unroll
        for (int nt = 0; nt < 2; ++nt) {
            const int n0 = (wave * 2 + nt) * 16;
            const float* wb = w_out + (size_t)(n0 + lm) * CH + lq * 8;
            bf16x8 bf[4];
            #pragma unroll
            for (int kt = 0; kt < 4; ++kt) {
                const float4 u0 = *(const float4*)(wb + kt * 32);
                const float4 u1 = *(const float4*)(wb + kt * 32 + 4);
                bf16x8 t;
                t[0] = (short)f2bs(u0.x); t[1] = (short)f2bs(u0.y);
                t[2] = (short)f2bs(u0.z); t[3] = (short)f2bs(u0.w);
                t[4] = (short)f2bs(u1.x); t[5] = (short)f2bs(u1.y);
                t[6] = (short)f2bs(u1.z); t[7] = (short)f2bs(u1.w);
                bf[kt] = t;
            }
            f32x4 c0 = {0.f,0.f,0.f,0.f}, c1 = {0.f,0.f,0.f,0.f};
            f32x4 c2 = {0.f,0.f,0.f,0.f}, c3 = {0.f,0.f,0.f,0.f};
            #pragma unroll
            for (int kt = 0; kt < 4; ++kt) {
                c0 = __builtin_amdgcn_mfma_f32_16x16x32_bf16(af[0][kt], bf[kt], c0, 0, 0, 0);
                c1 = __builtin_amdgcn_mfma_f32_16x16x32_bf16(af[1][kt], bf[kt], c1, 0, 0, 0);
                c2 = __builtin_amdgcn_mfma_f32_16x16x32_bf16(af[2][kt], bf[kt], c2, 0, 0, 0);
                c3 = __builtin_amdgcn_mfma_f32_16x16x32_bf16(af[3][kt], bf[kt], c3, 0, 0, 0);
            }
            const int col = n0 + lm;
            const float bo = b_out[col];
            #pragma unroll
            for (int mt = 0; mt < 4; ++mt) {
                const f32x4 c = (mt == 0) ? c0 : (mt == 1) ? c1 : (mt == 2) ? c2 : c3;
                const int rb = mt * 16 + lq * 4;
                #pragma unroll
                for (int r = 0; r < 4; ++r) {
                    const int s = rb + r;
                    if (s < S2) {
                        const int sy = s / 7, sx = s - sy * 7;
                        int gy = wh * 7 + sy + DSP; if (gy >= IMG) gy -= IMG;
                        int gx = ww * 7 + sx + DSP; if (gx >= IMG) gx -= IMG;
                        out[(size_t)((b * IMG + gy) * IMG + gx) * CH + col] = c[r] + bo;
                    }
                }
            }
        }
    }
}

extern "C" void kernel_launch(void* const* d_in, const int* in_sizes, int n_in,
                              void* d_out, int out_size, void* d_ws, size_t ws_size,
                              hipStream_t stream) {
    const float* x      = (const float*)d_in[0];
    const float* w_qkv  = (const float*)d_in[1];
    const float* pe     = (const float*)d_in[2];
    const float* w_out  = (const float*)d_in[3];
    const float* b_out  = (const float*)d_in[4];
    float* out = (float*)d_out;

    dim3 grid(64, 64);   // (windows, batch)
    swin_fused<<<grid, 256, 0, stream>>>(x, w_qkv, pe, w_out, b_out, out);
}

// Round 4
// 354.436 us; speedup vs baseline: 22.6726x; 1.7563x over previous
//
#include <hip/hip_runtime.h>
#include <hip/hip_bf16.h>

#define IMG 56
#define CH  128
#define S2  49
#define DSP 3

// ---- manual LDS layout (bytes), total 65384 <= 65536 ----
// ldsA  [0, 13328):      49 x 136 shorts. x-window bf16 (phase1 A), attn-out bf16 (phase4 A).
//                        (phase1/4 A-frag reads touch rows 49..63 -> in-bounds garbage, masked.)
// ldsQK [13328, 39200):  49 x 264 shorts; Q = cols 0..127, K = cols 128..255.
//                        AFTER the QK^T barrier this region is reused as 4 per-wave P buffers
//                        (wave w at byte offset w*6272; 49 rows x 64 shorts, XOR-swizzled).
// ldsVT [39200, 55584):  128 x 64 shorts (V transposed: [dim][key], keys 49..63 zeroed).
// mtab  [55584, 65384):  f32 49 x stride 50 (bias + shift-mask, shared by all 4 heads).
#define LDA   136
#define LDP   64
#define LDQK  264
#define LDVT  64
#define MTS   50
#define OFF_QK 13328
#define OFF_VT 39200
#define OFF_MT 55584
#define SMEM_BYTES 65384

typedef __attribute__((ext_vector_type(8))) short bf16x8;
typedef __attribute__((ext_vector_type(4))) float f32x4;

__device__ __forceinline__ unsigned short f2bs(float f) {   // f32 -> bf16 bits, RNE
    unsigned u = __float_as_uint(f);
    return (unsigned short)((u + 0x7fffu + ((u >> 16) & 1u)) >> 16);
}

__global__ __launch_bounds__(256, 2)
void swin_fused(const float* __restrict__ x,
                const float* __restrict__ w_qkv,
                const float* __restrict__ pe,
                const float* __restrict__ w_out,
                const float* __restrict__ b_out,
                float* __restrict__ out)
{
    __shared__ __align__(16) char smem[SMEM_BYTES];
    unsigned short* const ldsA  = (unsigned short*)smem;
    unsigned short* const ldsQK = (unsigned short*)(smem + OFF_QK);
    unsigned short* const ldsVT = (unsigned short*)(smem + OFF_VT);
    float*          const mtab  = (float*)(smem + OFF_MT);

    const int tid  = (int)threadIdx.x;
    const int wave = tid >> 6, lane = tid & 63;
    const int lm   = lane & 15, lq = lane >> 4;
    const int b    = (int)blockIdx.y;
    const int wh   = (int)blockIdx.x >> 3, ww = (int)blockIdx.x & 7;
    const bool my  = (wh == 7), mx = (ww == 7);

    // ---- phase 0: zero VT, build bias+mask table, stage rolled x-window as bf16 ----
    {
        unsigned long long* vz = (unsigned long long*)(smem + OFF_VT);
        for (int i = tid; i < 2048; i += 256) vz[i] = 0ull;     // 16384 B
    }
    for (int idx = tid; idx < S2 * S2; idx += 256) {
        const int i  = idx / 49, j = idx - i * 49;
        const int iy = i / 7, ix = i - iy * 7;
        const int jy = j / 7, jx = j - jy * 7;
        float v = pe[(jy - iy + 6) * 13 + (jx - ix + 6)];       // bias[i][j] = pe[c_j - c_i + 6]
        if (my && ((iy >= 4) != (jy >= 4))) v = -1e30f;
        if (mx && ((ix >= 4) != (jx >= 4))) v = -1e30f;
        mtab[i * MTS + j] = v;
    }
    for (int idx = tid; idx < S2 * 32; idx += 256) {
        const int s  = idx >> 5, c4 = (idx & 31) << 2;
        const int iy = s / 7, ix = s - iy * 7;
        int gy = wh * 7 + iy + DSP; if (gy >= IMG) gy -= IMG;
        int gx = ww * 7 + ix + DSP; if (gx >= IMG) gx -= IMG;
        const float4 v = *(const float4*)(x + (size_t)((b * IMG + gy) * IMG + gx) * CH + c4);
        uint2 p;
        p.x = (unsigned)f2bs(v.x) | ((unsigned)f2bs(v.y) << 16);
        p.y = (unsigned)f2bs(v.z) | ((unsigned)f2bs(v.w) << 16);
        *(uint2*)(ldsA + s * LDA + c4) = p;
    }
    __syncthreads();

    // ---- phase 1: qkv = A @ w_qkv^T (MFMA). Q,K row-major into ldsQK; V transposed into VT ----
    {
        bf16x8 af[4][4];
        #pragma unroll
        for (int mt = 0; mt < 4; ++mt)
            #pragma unroll
            for (int kt = 0; kt < 4; ++kt)
                af[mt][kt] = *(const bf16x8*)(ldsA + (mt * 16 + lm) * LDA + kt * 32 + lq * 8);

        #pragma unroll
        for (int nt = 0; nt < 6; ++nt) {
            const int n0 = (wave * 6 + nt) * 16;
            const float* wb = w_qkv + (size_t)(n0 + lm) * CH + lq * 8;
            bf16x8 bf[4];
            #pragma unroll
            for (int kt = 0; kt < 4; ++kt) {
                const float4 u0 = *(const float4*)(wb + kt * 32);
                const float4 u1 = *(const float4*)(wb + kt * 32 + 4);
                bf16x8 t;
                t[0] = (short)f2bs(u0.x); t[1] = (short)f2bs(u0.y);
                t[2] = (short)f2bs(u0.z); t[3] = (short)f2bs(u0.w);
                t[4] = (short)f2bs(u1.x); t[5] = (short)f2bs(u1.y);
                t[6] = (short)f2bs(u1.z); t[7] = (short)f2bs(u1.w);
                bf[kt] = t;
            }
            f32x4 c0 = {0.f,0.f,0.f,0.f}, c1 = {0.f,0.f,0.f,0.f};
            f32x4 c2 = {0.f,0.f,0.f,0.f}, c3 = {0.f,0.f,0.f,0.f};
            #pragma unroll
            for (int kt = 0; kt < 4; ++kt) {
                c0 = __builtin_amdgcn_mfma_f32_16x16x32_bf16(af[0][kt], bf[kt], c0, 0, 0, 0);
                c1 = __builtin_amdgcn_mfma_f32_16x16x32_bf16(af[1][kt], bf[kt], c1, 0, 0, 0);
                c2 = __builtin_amdgcn_mfma_f32_16x16x32_bf16(af[2][kt], bf[kt], c2, 0, 0, 0);
                c3 = __builtin_amdgcn_mfma_f32_16x16x32_bf16(af[3][kt], bf[kt], c3, 0, 0, 0);
            }
            const int col = n0 + lm;
            #pragma unroll
            for (int mt = 0; mt < 4; ++mt) {
                const f32x4 c = (mt == 0) ? c0 : (mt == 1) ? c1 : (mt == 2) ? c2 : c3;
                const int rb = mt * 16 + lq * 4;
                #pragma unroll
                for (int r = 0; r < 4; ++r) {
                    const int row = rb + r;
                    if (row < S2) {
                        const unsigned short hv = f2bs(c[r]);
                        if (col < 256) {
                            ldsQK[row * LDQK + col] = hv;
                        } else {
                            const int d   = col - 256;                // V dim 0..127
                            const int blk = (row >> 3) ^ (d & 7);     // XOR-block swizzle on key idx
                            ldsVT[d * LDVT + blk * 8 + (row & 7)] = hv;
                        }
                    }
                }
            }
        }
    }
    __syncthreads();

    // ---- phases 2+3: attention, wave = head, all on MFMA ----
    {
        const int h = wave;
        unsigned short* const ldsP = (unsigned short*)(smem + OFF_QK + wave * 6272);

        bf16x8 qa[4], kb[4];
        #pragma unroll
        for (int mt = 0; mt < 4; ++mt)
            qa[mt] = *(const bf16x8*)(ldsQK + (mt * 16 + lm) * LDQK + h * 32 + lq * 8);
        #pragma unroll
        for (int nt = 0; nt < 4; ++nt)
            kb[nt] = *(const bf16x8*)(ldsQK + (nt * 16 + lm) * LDQK + CH + h * 32 + lq * 8);

        f32x4 c[4][4];
        #pragma unroll
        for (int mt = 0; mt < 4; ++mt)
            #pragma unroll
            for (int nt = 0; nt < 4; ++nt) {
                f32x4 z = {0.f, 0.f, 0.f, 0.f};
                c[mt][nt] = __builtin_amdgcn_mfma_f32_16x16x32_bf16(qa[mt], kb[nt], z, 0, 0, 0);
            }

        __syncthreads();   // Q/K dead in LDS -> region becomes the P buffers

        bool colok[4];
        #pragma unroll
        for (int nt = 0; nt < 4; ++nt) colok[nt] = (nt * 16 + lm) < S2;

        // scale + bias + mask -> softmax (row lives in a 16-lane lm group)
        #pragma unroll
        for (int mt = 0; mt < 4; ++mt) {
            #pragma unroll
            for (int r = 0; r < 4; ++r) {
                const int row  = mt * 16 + lq * 4 + r;
                const int rowc = row < S2 ? row : (S2 - 1);
                const float* mrow = mtab + rowc * MTS + lm;
                #pragma unroll
                for (int nt = 0; nt < 4; ++nt) {
                    const float v = c[mt][nt][r] * 0.5f + mrow[nt * 16];
                    c[mt][nt][r] = colok[nt] ? v : -1e30f;
                }
                float mm = fmaxf(fmaxf(c[mt][0][r], c[mt][1][r]), fmaxf(c[mt][2][r], c[mt][3][r]));
                mm = fmaxf(mm, __shfl_xor(mm, 1));
                mm = fmaxf(mm, __shfl_xor(mm, 2));
                mm = fmaxf(mm, __shfl_xor(mm, 4));
                mm = fmaxf(mm, __shfl_xor(mm, 8));
                const float p0 = __expf(c[mt][0][r] - mm);
                const float p1 = __expf(c[mt][1][r] - mm);
                const float p2 = __expf(c[mt][2][r] - mm);
                const float p3 = __expf(c[mt][3][r] - mm);
                float ll = (p0 + p1) + (p2 + p3);
                ll += __shfl_xor(ll, 1);
                ll += __shfl_xor(ll, 2);
                ll += __shfl_xor(ll, 4);
                ll += __shfl_xor(ll, 8);
                const float inv = 1.0f / ll;
                c[mt][0][r] = p0 * inv; c[mt][1][r] = p1 * inv;
                c[mt][2][r] = p2 * inv; c[mt][3][r] = p3 * inv;
            }
        }

        // write P (bf16, XOR-swizzled); cols 49..63 are exact 0 (mask -> exp underflow)
        #pragma unroll
        for (int mt = 0; mt < 4; ++mt)
            #pragma unroll
            for (int r = 0; r < 4; ++r) {
                const int row = mt * 16 + lq * 4 + r;
                if (row < S2) {
                    #pragma unroll
                    for (int nt = 0; nt < 4; ++nt) {
                        const int col = nt * 16 + lm;
                        const int blk = (col >> 3) ^ (row & 7);
                        ldsP[row * LDP + blk * 8 + (col & 7)] = f2bs(c[mt][nt][r]);
                    }
                }
            }

        // PV: O = P @ V. A=P (per-wave LDS round-trip, in-order within wave), B=V from VT.
        bf16x8 pa[4][2], vb[2][2];
        #pragma unroll
        for (int mt = 0; mt < 4; ++mt) {
            const int row = mt * 16 + lm;
            #pragma unroll
            for (int kt = 0; kt < 2; ++kt) {
                const int blk = (kt * 4 + lq) ^ (row & 7);
                pa[mt][kt] = *(const bf16x8*)(ldsP + row * LDP + blk * 8);
            }
        }
        #pragma unroll
        for (int nt = 0; nt < 2; ++nt) {
            const int d = h * 32 + nt * 16 + lm;
            #pragma unroll
            for (int kt = 0; kt < 2; ++kt) {
                const int blk = (kt * 4 + lq) ^ (d & 7);
                vb[nt][kt] = *(const bf16x8*)(ldsVT + d * LDVT + blk * 8);
            }
        }
        f32x4 oc[4][2];
        #pragma unroll
        for (int mt = 0; mt < 4; ++mt)
            #pragma unroll
            for (int nt = 0; nt < 2; ++nt) {
                f32x4 z = {0.f, 0.f, 0.f, 0.f};
                z = __builtin_amdgcn_mfma_f32_16x16x32_bf16(pa[mt][0], vb[nt][0], z, 0, 0, 0);
                oc[mt][nt] = __builtin_amdgcn_mfma_f32_16x16x32_bf16(pa[mt][1], vb[nt][1], z, 0, 0, 0);
            }

        // attn-out -> ldsA (x-window is dead; P lives in the QK region, no conflict)
        #pragma unroll
        for (int mt = 0; mt < 4; ++mt)
            #pragma unroll
            for (int r = 0; r < 4; ++r) {
                const int row = mt * 16 + lq * 4 + r;
                if (row < S2) {
                    #pragma unroll
                    for (int nt = 0; nt < 2; ++nt)
                        ldsA[row * LDA + h * 32 + nt * 16 + lm] = f2bs(oc[mt][nt][r]);
                }
            }
    }
    __syncthreads();

    // ---- phase 4: out = attn @ w_out^T + b_out, scattered to rolled coords ----
    {
        bf16x8 af[4][4];
        #pragma unroll
        for (int mt = 0; mt < 4; ++mt)
            #pragma unroll
            for (int kt = 0; kt < 4; ++kt)
                af[mt][kt] = *(const bf16x8*)(ldsA + (mt * 16 + lm) * LDA + kt * 32 + lq * 8);

        #pragma unroll
        for (int nt = 0; nt < 2; ++nt) {
            const int n0 = (wave * 2 + nt) * 16;
            const float* wb = w_out + (size_t)(n0 + lm) * CH + lq * 8;
            bf16x8 bf[4];
            #pragma unroll
            for (int kt = 0; kt < 4; ++kt) {
                const float4 u0 = *(const float4*)(wb + kt * 32);
                const float4 u1 = *(const float4*)(wb + kt * 32 + 4);
                bf16x8 t;
                t[0] = (short)f2bs(u0.x); t[1] = (short)f2bs(u0.y);
                t[2] = (short)f2bs(u0.z); t[3] = (short)f2bs(u0.w);
                t[4] = (short)f2bs(u1.x); t[5] = (short)f2bs(u1.y);
                t[6] = (short)f2bs(u1.z); t[7] = (short)f2bs(u1.w);
                bf[kt] = t;
            }
            f32x4 c0 = {0.f,0.f,0.f,0.f}, c1 = {0.f,0.f,0.f,0.f};
            f32x4 c2 = {0.f,0.f,0.f,0.f}, c3 = {0.f,0.f,0.f,0.f};
            #pragma unroll
            for (int kt = 0; kt < 4; ++kt) {
                c0 = __builtin_amdgcn_mfma_f32_16x16x32_bf16(af[0][kt], bf[kt], c0, 0, 0, 0);
                c1 = __builtin_amdgcn_mfma_f32_16x16x32_bf16(af[1][kt], bf[kt], c1, 0, 0, 0);
                c2 = __builtin_amdgcn_mfma_f32_16x16x32_bf16(af[2][kt], bf[kt], c2, 0, 0, 0);
                c3 = __builtin_amdgcn_mfma_f32_16x16x32_bf16(af[3][kt], bf[kt], c3, 0, 0, 0);
            }
            const int col = n0 + lm;
            const float bo = b_out[col];
            #pragma unroll
            for (int mt = 0; mt < 4; ++mt) {
                const f32x4 c = (mt == 0) ? c0 : (mt == 1) ? c1 : (mt == 2) ? c2 : c3;
                const int rb = mt * 16 + lq * 4;
                #pragma unroll
                for (int r = 0; r < 4; ++r) {
                    const int s = rb + r;
                    if (s < S2) {
                        const int sy = s / 7, sx = s - sy * 7;
                        int gy = wh * 7 + sy + DSP; if (gy >= IMG) gy -= IMG;
                        int gx = ww * 7 + sx + DSP; if (gx >= IMG) gx -= IMG;
                        out[(size_t)((b * IMG + gy) * IMG + gx) * CH + col] = c[r] + bo;
                    }
                }
            }
        }
    }
}

extern "C" void kernel_launch(void* const* d_in, const int* in_sizes, int n_in,
                              void* d_out, int out_size, void* d_ws, size_t ws_size,
                              hipStream_t stream) {
    const float* x      = (const float*)d_in[0];
    const float* w_qkv  = (const float*)d_in[1];
    const float* pe     = (const float*)d_in[2];
    const float* w_out  = (const float*)d_in[3];
    const float* b_out  = (const float*)d_in[4];
    float* out = (float*)d_out;

    dim3 grid(64, 64);   // (windows, batch)
    swin_fused<<<grid, 256, 0, stream>>>(x, w_qkv, pe, w_out, b_out, out);
}